// Round 1
// baseline (3224.334 us; speedup 1.0000x reference)
//
#include <hip/hip_runtime.h>
#include <math.h>

// Llama forward on MI355X. Round 1: correctness-first full pipeline.
// ws layout (bytes): x f32 @0 (16.78MB), h bf16 @16MB.., qkv bf16, attnout bf16,
// u bf16, g bf16 (padded K 2752), Vt bf16, rope cos/sin tables. Total ~135MB.

using short8v = __attribute__((ext_vector_type(8))) short;
using f32x4   = __attribute__((ext_vector_type(4))) float;

__device__ __forceinline__ float b2f(short s) {
    union { unsigned u; float f; } v; v.u = ((unsigned)(unsigned short)s) << 16; return v.f;
}
__device__ __forceinline__ short f2b(float f) {
    union { float f; unsigned u; } v; v.f = f;
    unsigned r = v.u + 0x7FFFu + ((v.u >> 16) & 1u);
    return (short)(r >> 16);
}

// MFMA via inline asm (avoids builtin signature ambiguity). _f variant prefixes
// s_nop 1 to cover the SW-managed VALU-write -> MFMA-SrcC hazard (2 waits).
__device__ __forceinline__ void mfma_n(f32x4& d, short8v a, short8v b) {
    asm("v_mfma_f32_16x16x32_bf16 %0, %1, %2, %0" : "+v"(d) : "v"(a), "v"(b));
}
__device__ __forceinline__ void mfma_f(f32x4& d, short8v a, short8v b) {
    asm("s_nop 1\n\tv_mfma_f32_16x16x32_bf16 %0, %1, %2, %0" : "+v"(d) : "v"(a), "v"(b));
}
// MFMA-write -> VALU-read hazard fence (SW wait states; sched_barrier pins the nops).
#define MFMA_FENCE() do { __builtin_amdgcn_sched_barrier(0); \
    asm volatile("s_nop 7\n\ts_nop 7"); \
    __builtin_amdgcn_sched_barrier(0); } while (0)

// ---------------- rope tables ----------------
__global__ void rope_table_k(float* __restrict__ ct, float* __restrict__ st) {
    int i = blockIdx.x * 256 + threadIdx.x;   // 65536 = 2048 pos x 32 freqs
    int n = i >> 5, j = i & 31;
    float freq = expf(-(float)j * (9.210340371976184f / 32.f)); // 10000^(-j/32)
    float a = (float)n * freq;
    ct[i] = cosf(a);
    st[i] = sinf(a);
}

// ---------------- embedding gather ----------------
__global__ void embed_k(const int* __restrict__ tok, const float* __restrict__ emb,
                        float* __restrict__ x) {
    int row = blockIdx.x;
    int tk = tok[row];
    const float4* src = (const float4*)(emb + (size_t)tk * 1024);
    float4* dst = (float4*)(x + (size_t)row * 1024);
    dst[threadIdx.x] = src[threadIdx.x];
}

// ---------------- rmsnorm: f32 in -> bf16 out ----------------
__global__ void rmsnorm_k(const float* __restrict__ x, const float* __restrict__ wt,
                          short* __restrict__ out) {
    int row = blockIdx.x;
    int t = threadIdx.x;
    const float* xr = x + (size_t)row * 1024;
    float4 v = ((const float4*)xr)[t];
    float ss = v.x * v.x + v.y * v.y + v.z * v.z + v.w * v.w;
    #pragma unroll
    for (int off = 32; off > 0; off >>= 1) ss += __shfl_down(ss, off, 64);
    __shared__ float red[4];
    if ((t & 63) == 0) red[t >> 6] = ss;
    __syncthreads();
    float tot = red[0] + red[1] + red[2] + red[3];
    float inv = rsqrtf(tot * (1.f / 1024.f) + 1.1920929e-7f);
    float4 wv = ((const float4*)wt)[t];
    int2 pk;
    pk.x = (int)(unsigned short)f2b(v.x * inv * wv.x) |
           ((int)(unsigned short)f2b(v.y * inv * wv.y) << 16);
    pk.y = (int)(unsigned short)f2b(v.z * inv * wv.z) |
           ((int)(unsigned short)f2b(v.w * inv * wv.w) << 16);
    *(int2*)(out + (size_t)row * 1024 + t * 4) = pk;
}

// ---------------- rope apply (in-place on q,k sections of qkv, q scaled) ----------------
__global__ void rope_apply_k(short* __restrict__ qkv, const float* __restrict__ ct,
                             const float* __restrict__ st) {
    int gidx = blockIdx.x * 256 + threadIdx.x;  // 4096 rows * 32 hk * 32 j
    int j  = gidx & 31;
    int r  = (gidx >> 5) & 4095;
    int hk = gidx >> 17;                 // 0..31
    int qk = hk >> 4, h = hk & 15;
    int n = r & 2047;
    size_t base = (size_t)r * 3072 + (size_t)qk * 1024 + h * 64 + j;
    float a  = b2f(qkv[base]);
    float bv = b2f(qkv[base + 32]);
    float cc = ct[n * 32 + j], sv = st[n * 32 + j];
    float na = a * cc - bv * sv;
    float nb = bv * cc + a * sv;
    if (qk == 0) { na *= 0.125f; nb *= 0.125f; }   // q * dim_head^-0.5
    qkv[base]      = f2b(na);
    qkv[base + 32] = f2b(nb);
}

// ---------------- V transpose: qkv v-section [n][64] -> Vt [bh][64][2048] ----------------
__global__ void vt_k(const short* __restrict__ qkv, short* __restrict__ vt) {
    int id = blockIdx.x * 256 + threadIdx.x;  // 65536 8x8 tiles
    int dt = id & 7, nt = (id >> 3) & 255, bh = id >> 11;
    int b = bh >> 4, h = bh & 15;
    short s[8][8];
    #pragma unroll
    for (int r = 0; r < 8; ++r)
        *(int4*)s[r] = *(const int4*)(qkv + (size_t)(b * 2048 + nt * 8 + r) * 3072
                                      + 2048 + h * 64 + dt * 8);
    #pragma unroll
    for (int cc = 0; cc < 8; ++cc) {
        short o4[8];
        #pragma unroll
        for (int r = 0; r < 8; ++r) o4[r] = s[r][cc];
        *(int4*)(vt + (size_t)(bh * 64 + dt * 8 + cc) * 2048 + nt * 8) = *(int4*)o4;
    }
}

// ---------------- GEGLU ----------------
__global__ void geglu_k(const short* __restrict__ u, short* __restrict__ gbuf) {
    int r = blockIdx.x;
    int c = blockIdx.y * 256 + threadIdx.x;
    if (c >= 2752) return;
    float v = 0.f;
    if (c < 2730) {
        float u1 = b2f(u[(size_t)r * 5460 + c]);
        float gt = b2f(u[(size_t)r * 5460 + 2730 + c]);
        v = 0.5f * gt * (1.f + erff(gt * 0.7071067811865475f)) * u1;  // exact gelu
    }
    gbuf[(size_t)r * 2752 + c] = f2b(v);
}

// ---------------- GEMM: C[M=4096][N] = A_bf16[M][K] * W_f32[K][N] (+bias)(+res) ----------------
// 128x128 tile, BK=32, 4 waves (2x2), each wave 64x64 = 4x4 16x16x32 MFMAs.
// B staged transposed to [n][k] bf16 in LDS with kg ^= (n>>1)&3 swizzle (uniform banks).
template <bool BIAS, bool RES, bool OUTBF16>
__global__ __launch_bounds__(256, 2) void gemm_bf16(
    const short* __restrict__ A, const float* __restrict__ W,
    const float* __restrict__ bias, const float* __restrict__ res,
    void* __restrict__ outp, int N, int K, int lda, int ksteps) {
    __shared__ __align__(16) short As[128 * 32];
    __shared__ __align__(16) short Bs[128 * 32];
    const int t = threadIdx.x;
    const int lane = t & 63;
    const int w = t >> 6, wm = w >> 1, wn = w & 1;
    const int c = lane & 15, g = lane >> 4;
    const int m0 = blockIdx.y << 7;
    const int n0 = blockIdx.x << 7;

    f32x4 acc[4][4] = {};

    const int bn = t & 127, bkh = t >> 7;       // B-stage map
    const int arow = t >> 2, aseg = t & 3;      // A-stage map

    for (int kt = 0; kt < ksteps; ++kt) {
        const int k0 = kt << 5;
        __syncthreads();
        // stage A (already bf16): 2 x 16B per thread
        *(int4*)&As[arow * 32 + aseg * 8] =
            *(const int4*)(A + (size_t)(m0 + arow) * lda + k0 + aseg * 8);
        *(int4*)&As[(arow + 64) * 32 + aseg * 8] =
            *(const int4*)(A + (size_t)(m0 + arow + 64) * lda + k0 + aseg * 8);
        // stage B: f32 -> bf16, transposed to [n][k], swizzled
        {
            const int gn = n0 + bn;
            #pragma unroll
            for (int kh = bkh; kh < 4; kh += 2) {
                short tmp[8];
                #pragma unroll
                for (int i = 0; i < 8; ++i) {
                    int k = k0 + kh * 8 + i;
                    float v = 0.f;
                    if (k < K && gn < N) v = W[(size_t)k * N + gn];
                    tmp[i] = f2b(v);
                }
                int kg = kh ^ ((bn >> 1) & 3);
                *(int4*)&Bs[bn * 32 + kg * 8] = *(int4*)tmp;
            }
        }
        __syncthreads();
        short8v af[4], bf[4];
        #pragma unroll
        for (int mi = 0; mi < 4; ++mi)
            af[mi] = *(const short8v*)&As[(wm * 64 + mi * 16 + c) * 32 + g * 8];
        #pragma unroll
        for (int ni = 0; ni < 4; ++ni) {
            int ncol = wn * 64 + ni * 16 + c;
            int kg = g ^ ((ncol >> 1) & 3);
            bf[ni] = *(const short8v*)&Bs[ncol * 32 + kg * 8];
        }
        #pragma unroll
        for (int mi = 0; mi < 4; ++mi)
            #pragma unroll
            for (int ni = 0; ni < 4; ++ni)
                mfma_n(acc[mi][ni], af[mi], bf[ni]);
    }
    MFMA_FENCE();
    #pragma unroll
    for (int mi = 0; mi < 4; ++mi) {
        #pragma unroll
        for (int ni = 0; ni < 4; ++ni) {
            int col = n0 + wn * 64 + ni * 16 + c;
            if (col < N) {
                float bv = BIAS ? bias[col] : 0.f;
                #pragma unroll
                for (int i = 0; i < 4; ++i) {
                    int row = m0 + wm * 64 + mi * 16 + g * 4 + i;
                    size_t off = (size_t)row * N + col;
                    float v = acc[mi][ni][i] + bv;
                    if (RES) v += res[off];
                    if (OUTBF16) ((short*)outp)[off] = f2b(v);
                    else         ((float*)outp)[off] = v;
                }
            }
        }
    }
}

// ---------------- flash attention: grid (qt=16, bh=32), 4 waves, q-tile 128 ----------------
__global__ __launch_bounds__(256, 2) void attn_fwd(
    const short* __restrict__ qkv, const short* __restrict__ vt,
    short* __restrict__ o) {
    const int qt = blockIdx.x, bh = blockIdx.y;
    const int b = bh >> 4, h = bh & 15;
    const int t = threadIdx.x, lane = t & 63, w = t >> 6;
    const int c = lane & 15, g = lane >> 4;
    __shared__ __align__(16) short Ks[128 * 72];
    __shared__ __align__(16) short Vs[64 * 136];
    __shared__ __align__(16) short Ps[128 * 136];   // also Q staging buffer

    // stage Q tile through Ps
    #pragma unroll
    for (int i = 0; i < 4; ++i) {
        int idx = t + i * 256, r = idx >> 3, seg = idx & 7;
        *(int4*)&Ps[r * 136 + seg * 8] =
            *(const int4*)(qkv + (size_t)(b * 2048 + qt * 128 + r) * 3072 + h * 64 + seg * 8);
    }
    __syncthreads();
    short8v qf[2][2];
    #pragma unroll
    for (int mi = 0; mi < 2; ++mi)
        #pragma unroll
        for (int kk = 0; kk < 2; ++kk)
            qf[mi][kk] = *(const short8v*)&Ps[(w * 32 + mi * 16 + c) * 136 + kk * 32 + g * 8];

    f32x4 oacc[2][4] = {};
    float mrow[2][4], lrow[2][4];
    #pragma unroll
    for (int mi = 0; mi < 2; ++mi)
        #pragma unroll
        for (int i = 0; i < 4; ++i) { mrow[mi][i] = -3.0e38f; lrow[mi][i] = 0.f; }

    for (int jt = 0; jt <= qt; ++jt) {
        __syncthreads();
        #pragma unroll
        for (int i = 0; i < 4; ++i) {   // stage K [128][64] -> [128][72]
            int idx = t + i * 256, r = idx >> 3, seg = idx & 7;
            *(int4*)&Ks[r * 72 + seg * 8] =
                *(const int4*)(qkv + (size_t)(b * 2048 + jt * 128 + r) * 3072
                               + 1024 + h * 64 + seg * 8);
        }
        #pragma unroll
        for (int i = 0; i < 4; ++i) {   // stage Vt [64][128] -> [64][136]
            int idx = t + i * 256, d = idx >> 4, seg = idx & 15;
            *(int4*)&Vs[d * 136 + seg * 8] =
                *(const int4*)(vt + (size_t)(bh * 64 + d) * 2048 + jt * 128 + seg * 8);
        }
        __syncthreads();
        // S = Q K^T  (wave: 32 q rows x 128 kv)
        f32x4 sacc[2][8] = {};
        #pragma unroll
        for (int kk = 0; kk < 2; ++kk) {
            short8v kf[8];
            #pragma unroll
            for (int ni = 0; ni < 8; ++ni)
                kf[ni] = *(const short8v*)&Ks[(ni * 16 + c) * 72 + kk * 32 + g * 8];
            #pragma unroll
            for (int mi = 0; mi < 2; ++mi)
                #pragma unroll
                for (int ni = 0; ni < 8; ++ni) {
                    if (kk == 0) mfma_f(sacc[mi][ni], qf[mi][kk], kf[ni]);
                    else         mfma_n(sacc[mi][ni], qf[mi][kk], kf[ni]);
                }
        }
        MFMA_FENCE();
        if (jt == qt) {   // causal mask on diagonal tile
            #pragma unroll
            for (int mi = 0; mi < 2; ++mi)
                #pragma unroll
                for (int ni = 0; ni < 8; ++ni)
                    #pragma unroll
                    for (int i = 0; i < 4; ++i) {
                        int qrow = w * 32 + mi * 16 + g * 4 + i;
                        int kcol = ni * 16 + c;
                        if (kcol > qrow) sacc[mi][ni][i] = -3.0e38f;
                    }
        }
        // online softmax (row reduce over 8 frags + 16-lane butterfly)
        #pragma unroll
        for (int mi = 0; mi < 2; ++mi) {
            #pragma unroll
            for (int i = 0; i < 4; ++i) {
                float mx = sacc[mi][0][i];
                #pragma unroll
                for (int ni = 1; ni < 8; ++ni) mx = fmaxf(mx, sacc[mi][ni][i]);
                #pragma unroll
                for (int off = 1; off < 16; off <<= 1) mx = fmaxf(mx, __shfl_xor(mx, off, 64));
                float mnew = fmaxf(mrow[mi][i], mx);
                float alpha = __expf(mrow[mi][i] - mnew);
                mrow[mi][i] = mnew;
                float ls = 0.f;
                #pragma unroll
                for (int ni = 0; ni < 8; ++ni) {
                    float p = __expf(sacc[mi][ni][i] - mnew);
                    sacc[mi][ni][i] = p;
                    ls += p;
                }
                #pragma unroll
                for (int off = 1; off < 16; off <<= 1) ls += __shfl_xor(ls, off, 64);
                lrow[mi][i] = lrow[mi][i] * alpha + ls;
                #pragma unroll
                for (int df = 0; df < 4; ++df) oacc[mi][df][i] *= alpha;
            }
        }
        // P -> LDS (bf16, own rows only)
        #pragma unroll
        for (int mi = 0; mi < 2; ++mi)
            #pragma unroll
            for (int ni = 0; ni < 8; ++ni)
                #pragma unroll
                for (int i = 0; i < 4; ++i)
                    Ps[(w * 32 + mi * 16 + g * 4 + i) * 136 + ni * 16 + c] =
                        f2b(sacc[mi][ni][i]);
        // O += P * V
        #pragma unroll
        for (int kk = 0; kk < 4; ++kk) {
            short8v pf[2], vf[4];
            #pragma unroll
            for (int mi = 0; mi < 2; ++mi)
                pf[mi] = *(const short8v*)&Ps[(w * 32 + mi * 16 + c) * 136 + kk * 32 + g * 8];
            #pragma unroll
            for (int df = 0; df < 4; ++df)
                vf[df] = *(const short8v*)&Vs[(df * 16 + c) * 136 + kk * 32 + g * 8];
            #pragma unroll
            for (int mi = 0; mi < 2; ++mi)
                #pragma unroll
                for (int df = 0; df < 4; ++df) {
                    if (kk == 0) mfma_f(oacc[mi][df], pf[mi], vf[df]);
                    else         mfma_n(oacc[mi][df], pf[mi], vf[df]);
                }
        }
    }
    MFMA_FENCE();
    #pragma unroll
    for (int mi = 0; mi < 2; ++mi)
        #pragma unroll
        for (int df = 0; df < 4; ++df)
            #pragma unroll
            for (int i = 0; i < 4; ++i) {
                int qrow = qt * 128 + w * 32 + mi * 16 + g * 4 + i;
                float v = oacc[mi][df][i] / lrow[mi][i];
                o[(size_t)(b * 2048 + qrow) * 1024 + h * 64 + df * 16 + c] = f2b(v);
            }
}

extern "C" void kernel_launch(void* const* d_in, const int* in_sizes, int n_in,
                              void* d_out, int out_size, void* d_ws, size_t ws_size,
                              hipStream_t stream) {
    (void)in_sizes; (void)n_in; (void)out_size; (void)ws_size;
    const int*   tokens = (const int*)d_in[0];
    const float* temb   = (const float*)d_in[1];
    const float* anw    = (const float*)d_in[2];
    const float* wqkv   = (const float*)d_in[3];
    const float* wo     = (const float*)d_in[4];
    const float* fnw    = (const float*)d_in[5];
    const float* fw1    = (const float*)d_in[6];
    const float* fb1    = (const float*)d_in[7];
    const float* fw2    = (const float*)d_in[8];
    const float* fb2    = (const float*)d_in[9];
    const float* finw   = (const float*)d_in[10];
    const float* lw     = (const float*)d_in[11];
    const float* lb     = (const float*)d_in[12];

    char* ws = (char*)d_ws;
    float* x   = (float*)(ws + 0);            // 4096x1024 f32
    short* hb  = (short*)(ws + 16777216);     // 4096x1024 bf16
    short* qkv = (short*)(ws + 25165824);     // 4096x3072 bf16
    short* ao  = (short*)(ws + 50331648);     // 4096x1024 bf16
    short* ub  = (short*)(ws + 58720256);     // 4096x5460 bf16
    short* gb  = (short*)(ws + 103448576);    // 4096x2752 bf16 (K-padded)
    short* vtb = (short*)(ws + 125992960);    // 32x64x2048 bf16
    float* ct  = (float*)(ws + 134381568);    // 2048x32 f32
    float* st  = (float*)(ws + 134643712);    // 2048x32 f32

    rope_table_k<<<256, 256, 0, stream>>>(ct, st);
    embed_k<<<4096, 256, 0, stream>>>(tokens, temb, x);

    for (int l = 0; l < 4; ++l) {
        rmsnorm_k<<<4096, 256, 0, stream>>>(x, anw + l * 1024, hb);
        gemm_bf16<false, false, true><<<dim3(24, 32), 256, 0, stream>>>(
            hb, wqkv + (size_t)l * 1024 * 3072, nullptr, nullptr, qkv, 3072, 1024, 1024, 32);
        rope_apply_k<<<16384, 256, 0, stream>>>(qkv, ct, st);
        vt_k<<<256, 256, 0, stream>>>(qkv, vtb);
        attn_fwd<<<dim3(16, 32), 256, 0, stream>>>(qkv, vtb, ao);
        gemm_bf16<false, true, false><<<dim3(8, 32), 256, 0, stream>>>(
            ao, wo + (size_t)l * 1024 * 1024, nullptr, x, x, 1024, 1024, 1024, 32);
        rmsnorm_k<<<4096, 256, 0, stream>>>(x, fnw + l * 1024, hb);
        gemm_bf16<true, false, true><<<dim3(43, 32), 256, 0, stream>>>(
            hb, fw1 + (size_t)l * 1024 * 5460, fb1 + l * 5460, nullptr, ub, 5460, 1024, 1024, 32);
        geglu_k<<<dim3(4096, 11), 256, 0, stream>>>(ub, gb);
        gemm_bf16<true, true, false><<<dim3(8, 32), 256, 0, stream>>>(
            gb, fw2 + (size_t)l * 2730 * 1024, fb2 + l * 1024, x, x, 1024, 2730, 2752, 86);
    }
    rmsnorm_k<<<4096, 256, 0, stream>>>(x, finw, hb);
    gemm_bf16<true, false, false><<<dim3(250, 32), 256, 0, stream>>>(
        hb, lw, lb, nullptr, d_out, 32000, 1024, 1024, 32);
}

// Round 2
// 2105.175 us; speedup vs baseline: 1.5316x; 1.5316x over previous
//
#include <hip/hip_runtime.h>
#include <math.h>
#include <stdint.h>

// Llama forward on MI355X. Round 2: bf16 pre-transposed weights + m97-style
// global_load_lds GEMM (128x128 tile, BK=32, 4 waves, 16 MFMA/K-step).

using short8v = __attribute__((ext_vector_type(8))) short;
using f32x4   = __attribute__((ext_vector_type(4))) float;

__device__ __forceinline__ float b2f(short s) {
    union { unsigned u; float f; } v; v.u = ((unsigned)(unsigned short)s) << 16; return v.f;
}
__device__ __forceinline__ short f2b(float f) {
    union { float f; unsigned u; } v; v.f = f;
    unsigned r = v.u + 0x7FFFu + ((v.u >> 16) & 1u);
    return (short)(r >> 16);
}

__device__ __forceinline__ void mfma_n(f32x4& d, short8v a, short8v b) {
    asm("v_mfma_f32_16x16x32_bf16 %0, %1, %2, %0" : "+v"(d) : "v"(a), "v"(b));
}
__device__ __forceinline__ void mfma_f(f32x4& d, short8v a, short8v b) {
    asm("s_nop 1\n\tv_mfma_f32_16x16x32_bf16 %0, %1, %2, %0" : "+v"(d) : "v"(a), "v"(b));
}
#define MFMA_FENCE() do { __builtin_amdgcn_sched_barrier(0); \
    asm volatile("s_nop 7\n\ts_nop 7"); \
    __builtin_amdgcn_sched_barrier(0); } while (0)

// async global->LDS, 16B per lane. LDS ptr must be wave-uniform.
__device__ __forceinline__ void gload16(const void* g, void* l) {
    __builtin_amdgcn_global_load_lds(
        (const __attribute__((address_space(1))) unsigned int*)(uintptr_t)g,
        (__attribute__((address_space(3))) unsigned int*)(uintptr_t)l,
        16, 0, 0);
}

// ---------------- rope tables ----------------
__global__ void rope_table_k(float* __restrict__ ct, float* __restrict__ st) {
    int i = blockIdx.x * 256 + threadIdx.x;   // 65536 = 2048 pos x 32 freqs
    int n = i >> 5, j = i & 31;
    float freq = expf(-(float)j * (9.210340371976184f / 32.f)); // 10000^(-j/32)
    float a = (float)n * freq;
    ct[i] = cosf(a);
    st[i] = sinf(a);
}

// ---------------- embedding gather ----------------
__global__ void embed_k(const int* __restrict__ tok, const float* __restrict__ emb,
                        float* __restrict__ x) {
    int row = blockIdx.x;
    int tk = tok[row];
    const float4* src = (const float4*)(emb + (size_t)tk * 1024);
    float4* dst = (float4*)(x + (size_t)row * 1024);
    dst[threadIdx.x] = src[threadIdx.x];
}

// ---------------- weight convert+transpose: f32 [K][N] -> bf16 [Npad][Kpad] ----------------
// grid (Npad/32, Kpad/32, L), 256 threads. Zero-fills pads.
__global__ void wconv_k(const float* __restrict__ W, short* __restrict__ T,
                        int K, int N, int Kpad,
                        size_t w_lstride, size_t t_lstride) {
    W += blockIdx.z * w_lstride;
    T += blockIdx.z * t_lstride;
    int n0 = blockIdx.x * 32, k0 = blockIdx.y * 32;
    __shared__ float tile[32][33];
    int t = threadIdx.x;
    int kk = t >> 3, ns = (t & 7) * 4;
    float4 v = make_float4(0.f, 0.f, 0.f, 0.f);
    int gk = k0 + kk;
    if (gk < K) {
        if (n0 + ns + 3 < N) {
            v = *(const float4*)(W + (size_t)gk * N + n0 + ns);
        } else {
            float tmp[4] = {0.f, 0.f, 0.f, 0.f};
            #pragma unroll
            for (int j = 0; j < 4; ++j)
                if (n0 + ns + j < N) tmp[j] = W[(size_t)gk * N + n0 + ns + j];
            v = make_float4(tmp[0], tmp[1], tmp[2], tmp[3]);
        }
    }
    tile[kk][ns + 0] = v.x; tile[kk][ns + 1] = v.y;
    tile[kk][ns + 2] = v.z; tile[kk][ns + 3] = v.w;
    __syncthreads();
    int nn = t >> 3, ks = (t & 7) * 4;
    short o[4];
    #pragma unroll
    for (int j = 0; j < 4; ++j) o[j] = f2b(tile[ks + j][nn]);
    *(int2*)(T + (size_t)(n0 + nn) * Kpad + k0 + ks) = *(int2*)o;
}

// ---------------- rmsnorm: f32 in -> bf16 out ----------------
__global__ void rmsnorm_k(const float* __restrict__ x, const float* __restrict__ wt,
                          short* __restrict__ out) {
    int row = blockIdx.x;
    int t = threadIdx.x;
    const float* xr = x + (size_t)row * 1024;
    float4 v = ((const float4*)xr)[t];
    float ss = v.x * v.x + v.y * v.y + v.z * v.z + v.w * v.w;
    #pragma unroll
    for (int off = 32; off > 0; off >>= 1) ss += __shfl_down(ss, off, 64);
    __shared__ float red[4];
    if ((t & 63) == 0) red[t >> 6] = ss;
    __syncthreads();
    float tot = red[0] + red[1] + red[2] + red[3];
    float inv = rsqrtf(tot * (1.f / 1024.f) + 1.1920929e-7f);
    float4 wv = ((const float4*)wt)[t];
    int2 pk;
    pk.x = (int)(unsigned short)f2b(v.x * inv * wv.x) |
           ((int)(unsigned short)f2b(v.y * inv * wv.y) << 16);
    pk.y = (int)(unsigned short)f2b(v.z * inv * wv.z) |
           ((int)(unsigned short)f2b(v.w * inv * wv.w) << 16);
    *(int2*)(out + (size_t)row * 1024 + t * 4) = pk;
}

// ---------------- rope apply (in-place on q,k sections of qkv, q scaled) ----------------
__global__ void rope_apply_k(short* __restrict__ qkv, const float* __restrict__ ct,
                             const float* __restrict__ st) {
    int gidx = blockIdx.x * 256 + threadIdx.x;  // 4096 rows * 32 hk * 32 j
    int j  = gidx & 31;
    int r  = (gidx >> 5) & 4095;
    int hk = gidx >> 17;                 // 0..31
    int qk = hk >> 4, h = hk & 15;
    int n = r & 2047;
    size_t base = (size_t)r * 3072 + (size_t)qk * 1024 + h * 64 + j;
    float a  = b2f(qkv[base]);
    float bv = b2f(qkv[base + 32]);
    float cc = ct[n * 32 + j], sv = st[n * 32 + j];
    float na = a * cc - bv * sv;
    float nb = bv * cc + a * sv;
    if (qk == 0) { na *= 0.125f; nb *= 0.125f; }   // q * dim_head^-0.5
    qkv[base]      = f2b(na);
    qkv[base + 32] = f2b(nb);
}

// ---------------- V transpose: qkv v-section [n][64] -> Vt [bh][64][2048] ----------------
__global__ void vt_k(const short* __restrict__ qkv, short* __restrict__ vt) {
    int id = blockIdx.x * 256 + threadIdx.x;  // 65536 8x8 tiles
    int dt = id & 7, nt = (id >> 3) & 255, bh = id >> 11;
    int b = bh >> 4, h = bh & 15;
    short s[8][8];
    #pragma unroll
    for (int r = 0; r < 8; ++r)
        *(int4*)s[r] = *(const int4*)(qkv + (size_t)(b * 2048 + nt * 8 + r) * 3072
                                      + 2048 + h * 64 + dt * 8);
    #pragma unroll
    for (int cc = 0; cc < 8; ++cc) {
        short o4[8];
        #pragma unroll
        for (int r = 0; r < 8; ++r) o4[r] = s[r][cc];
        *(int4*)(vt + (size_t)(bh * 64 + dt * 8 + cc) * 2048 + nt * 8) = *(int4*)o4;
    }
}

// ---------------- GEGLU ----------------
__global__ void geglu_k(const short* __restrict__ u, short* __restrict__ gbuf) {
    int r = blockIdx.x;
    int c = blockIdx.y * 256 + threadIdx.x;
    if (c >= 2752) return;
    float v = 0.f;
    if (c < 2730) {
        float u1 = b2f(u[(size_t)r * 5460 + c]);
        float gt = b2f(u[(size_t)r * 5460 + 2730 + c]);
        v = 0.5f * gt * (1.f + erff(gt * 0.7071067811865475f)) * u1;  // exact gelu
    }
    gbuf[(size_t)r * 2752 + c] = f2b(v);
}

// ---------------- GEMM: C[4096][N] = A_bf16[4096][lda] * Bt_bf16[Npad][ldb]^T ----------------
// m97 structure: 128x128 tile, BK=32, 4 waves (2x2), global_load_lds staging,
// 1-D grid with bijective XCD swizzle, m-fastest (weight-panel locality).
template <bool BIAS, bool RES, bool OUTBF16>
__global__ __launch_bounds__(256, 2) void gemm2(
    const short* __restrict__ A, const short* __restrict__ Bt,
    const float* __restrict__ bias, const float* __restrict__ res,
    void* __restrict__ outp, int N, int lda, int ldb, int ksteps) {
    __shared__ __align__(16) short As[128 * 32];
    __shared__ __align__(16) short Bs[128 * 32];
    const int t = threadIdx.x;
    const int lane = t & 63;
    const int w = t >> 6, wm = w >> 1, wn = w & 1;
    const int c = lane & 15, g = lane >> 4;

    const int nwg = (int)gridDim.x;           // 32 * nblocks, % 8 == 0
    const int cpx = nwg >> 3;
    const int wg = ((int)blockIdx.x & 7) * cpx + ((int)blockIdx.x >> 3);
    const int m0 = (wg & 31) << 7;
    const int n0 = (wg >> 5) << 7;

    // staging map: wave w owns LDS chunks 2w, 2w+1 (16 rows x 32 elems each)
    const int srow = w * 32 + (lane >> 2);
    const int sseg = (lane & 3) * 8;
    const short* ga0 = A  + (size_t)(m0 + srow) * lda + sseg;
    const short* ga1 = A  + (size_t)(m0 + srow + 16) * lda + sseg;
    const short* gb0 = Bt + (size_t)(n0 + srow) * ldb + sseg;
    const short* gb1 = Bt + (size_t)(n0 + srow + 16) * ldb + sseg;
    short* la0 = &As[(w * 2 + 0) * 512];
    short* la1 = &As[(w * 2 + 1) * 512];
    short* lb0 = &Bs[(w * 2 + 0) * 512];
    short* lb1 = &Bs[(w * 2 + 1) * 512];

    f32x4 acc[4][4] = {};

    for (int kt = 0; kt < ksteps; ++kt) {
        const int k0 = kt << 5;
        __syncthreads();
        gload16(ga0 + k0, la0);
        gload16(ga1 + k0, la1);
        gload16(gb0 + k0, lb0);
        gload16(gb1 + k0, lb1);
        __syncthreads();
        short8v af[4], bf[4];
        #pragma unroll
        for (int mi = 0; mi < 4; ++mi)
            af[mi] = *(const short8v*)&As[(wm * 64 + mi * 16 + c) * 32 + g * 8];
        #pragma unroll
        for (int ni = 0; ni < 4; ++ni)
            bf[ni] = *(const short8v*)&Bs[(wn * 64 + ni * 16 + c) * 32 + g * 8];
        #pragma unroll
        for (int mi = 0; mi < 4; ++mi)
            #pragma unroll
            for (int ni = 0; ni < 4; ++ni)
                mfma_n(acc[mi][ni], af[mi], bf[ni]);
    }
    MFMA_FENCE();
    #pragma unroll
    for (int mi = 0; mi < 4; ++mi) {
        #pragma unroll
        for (int ni = 0; ni < 4; ++ni) {
            int col = n0 + wn * 64 + ni * 16 + c;
            if (col < N) {
                float bv = BIAS ? bias[col] : 0.f;
                #pragma unroll
                for (int i = 0; i < 4; ++i) {
                    int row = m0 + wm * 64 + mi * 16 + g * 4 + i;
                    size_t off = (size_t)row * N + col;
                    float v = acc[mi][ni][i] + bv;
                    if (RES) v += res[off];
                    if (OUTBF16) ((short*)outp)[off] = f2b(v);
                    else         ((float*)outp)[off] = v;
                }
            }
        }
    }
}

// ---------------- flash attention: grid (qt=16, bh=32), 4 waves, q-tile 128 ----------------
__global__ __launch_bounds__(256, 2) void attn_fwd(
    const short* __restrict__ qkv, const short* __restrict__ vt,
    short* __restrict__ o) {
    const int qt = blockIdx.x, bh = blockIdx.y;
    const int b = bh >> 4, h = bh & 15;
    const int t = threadIdx.x, lane = t & 63, w = t >> 6;
    const int c = lane & 15, g = lane >> 4;
    __shared__ __align__(16) short Ks[128 * 72];
    __shared__ __align__(16) short Vs[64 * 136];
    __shared__ __align__(16) short Ps[128 * 136];   // also Q staging buffer

    #pragma unroll
    for (int i = 0; i < 4; ++i) {
        int idx = t + i * 256, r = idx >> 3, seg = idx & 7;
        *(int4*)&Ps[r * 136 + seg * 8] =
            *(const int4*)(qkv + (size_t)(b * 2048 + qt * 128 + r) * 3072 + h * 64 + seg * 8);
    }
    __syncthreads();
    short8v qf[2][2];
    #pragma unroll
    for (int mi = 0; mi < 2; ++mi)
        #pragma unroll
        for (int kk = 0; kk < 2; ++kk)
            qf[mi][kk] = *(const short8v*)&Ps[(w * 32 + mi * 16 + c) * 136 + kk * 32 + g * 8];

    f32x4 oacc[2][4] = {};
    float mrow[2][4], lrow[2][4];
    #pragma unroll
    for (int mi = 0; mi < 2; ++mi)
        #pragma unroll
        for (int i = 0; i < 4; ++i) { mrow[mi][i] = -3.0e38f; lrow[mi][i] = 0.f; }

    for (int jt = 0; jt <= qt; ++jt) {
        __syncthreads();
        #pragma unroll
        for (int i = 0; i < 4; ++i) {   // stage K [128][64] -> [128][72]
            int idx = t + i * 256, r = idx >> 3, seg = idx & 7;
            *(int4*)&Ks[r * 72 + seg * 8] =
                *(const int4*)(qkv + (size_t)(b * 2048 + jt * 128 + r) * 3072
                               + 1024 + h * 64 + seg * 8);
        }
        #pragma unroll
        for (int i = 0; i < 4; ++i) {   // stage Vt [64][128] -> [64][136]
            int idx = t + i * 256, d = idx >> 4, seg = idx & 15;
            *(int4*)&Vs[d * 136 + seg * 8] =
                *(const int4*)(vt + (size_t)(bh * 64 + d) * 2048 + jt * 128 + seg * 8);
        }
        __syncthreads();
        f32x4 sacc[2][8] = {};
        #pragma unroll
        for (int kk = 0; kk < 2; ++kk) {
            short8v kf[8];
            #pragma unroll
            for (int ni = 0; ni < 8; ++ni)
                kf[ni] = *(const short8v*)&Ks[(ni * 16 + c) * 72 + kk * 32 + g * 8];
            #pragma unroll
            for (int mi = 0; mi < 2; ++mi)
                #pragma unroll
                for (int ni = 0; ni < 8; ++ni) {
                    if (kk == 0) mfma_f(sacc[mi][ni], qf[mi][kk], kf[ni]);
                    else         mfma_n(sacc[mi][ni], qf[mi][kk], kf[ni]);
                }
        }
        MFMA_FENCE();
        if (jt == qt) {
            #pragma unroll
            for (int mi = 0; mi < 2; ++mi)
                #pragma unroll
                for (int ni = 0; ni < 8; ++ni)
                    #pragma unroll
                    for (int i = 0; i < 4; ++i) {
                        int qrow = w * 32 + mi * 16 + g * 4 + i;
                        int kcol = ni * 16 + c;
                        if (kcol > qrow) sacc[mi][ni][i] = -3.0e38f;
                    }
        }
        #pragma unroll
        for (int mi = 0; mi < 2; ++mi) {
            #pragma unroll
            for (int i = 0; i < 4; ++i) {
                float mx = sacc[mi][0][i];
                #pragma unroll
                for (int ni = 1; ni < 8; ++ni) mx = fmaxf(mx, sacc[mi][ni][i]);
                #pragma unroll
                for (int off = 1; off < 16; off <<= 1) mx = fmaxf(mx, __shfl_xor(mx, off, 64));
                float mnew = fmaxf(mrow[mi][i], mx);
                float alpha = __expf(mrow[mi][i] - mnew);
                mrow[mi][i] = mnew;
                float ls = 0.f;
                #pragma unroll
                for (int ni = 0; ni < 8; ++ni) {
                    float p = __expf(sacc[mi][ni][i] - mnew);
                    sacc[mi][ni][i] = p;
                    ls += p;
                }
                #pragma unroll
                for (int off = 1; off < 16; off <<= 1) ls += __shfl_xor(ls, off, 64);
                lrow[mi][i] = lrow[mi][i] * alpha + ls;
                #pragma unroll
                for (int df = 0; df < 4; ++df) oacc[mi][df][i] *= alpha;
            }
        }
        #pragma unroll
        for (int mi = 0; mi < 2; ++mi)
            #pragma unroll
            for (int ni = 0; ni < 8; ++ni)
                #pragma unroll
                for (int i = 0; i < 4; ++i)
                    Ps[(w * 32 + mi * 16 + g * 4 + i) * 136 + ni * 16 + c] =
                        f2b(sacc[mi][ni][i]);
        #pragma unroll
        for (int kk = 0; kk < 4; ++kk) {
            short8v pf[2], vf[4];
            #pragma unroll
            for (int mi = 0; mi < 2; ++mi)
                pf[mi] = *(const short8v*)&Ps[(w * 32 + mi * 16 + c) * 136 + kk * 32 + g * 8];
            #pragma unroll
            for (int df = 0; df < 4; ++df)
                vf[df] = *(const short8v*)&Vs[(df * 16 + c) * 136 + kk * 32 + g * 8];
            #pragma unroll
            for (int mi = 0; mi < 2; ++mi)
                #pragma unroll
                for (int df = 0; df < 4; ++df) {
                    if (kk == 0) mfma_f(oacc[mi][df], pf[mi], vf[df]);
                    else         mfma_n(oacc[mi][df], pf[mi], vf[df]);
                }
        }
    }
    MFMA_FENCE();
    #pragma unroll
    for (int mi = 0; mi < 2; ++mi)
        #pragma unroll
        for (int df = 0; df < 4; ++df)
            #pragma unroll
            for (int i = 0; i < 4; ++i) {
                int qrow = qt * 128 + w * 32 + mi * 16 + g * 4 + i;
                float v = oacc[mi][df][i] / lrow[mi][i];
                o[(size_t)(b * 2048 + qrow) * 1024 + h * 64 + df * 16 + c] = f2b(v);
            }
}

extern "C" void kernel_launch(void* const* d_in, const int* in_sizes, int n_in,
                              void* d_out, int out_size, void* d_ws, size_t ws_size,
                              hipStream_t stream) {
    (void)in_sizes; (void)n_in; (void)out_size; (void)ws_size;
    const int*   tokens = (const int*)d_in[0];
    const float* temb   = (const float*)d_in[1];
    const float* anw    = (const float*)d_in[2];
    const float* wqkv   = (const float*)d_in[3];
    const float* wo     = (const float*)d_in[4];
    const float* fnw    = (const float*)d_in[5];
    const float* fw1    = (const float*)d_in[6];
    const float* fb1    = (const float*)d_in[7];
    const float* fw2    = (const float*)d_in[8];
    const float* fb2    = (const float*)d_in[9];
    const float* finw   = (const float*)d_in[10];
    const float* lw     = (const float*)d_in[11];
    const float* lb     = (const float*)d_in[12];

    char* ws = (char*)d_ws;
    float* x    = (float*)(ws + 0);            // 4096x1024 f32
    short* hb   = (short*)(ws + 16777216);     // 4096x1024 bf16
    short* qkv  = (short*)(ws + 25165824);     // 4096x3072 bf16
    short* ao   = (short*)(ws + 50331648);     // 4096x1024 bf16
    short* ub   = (short*)(ws + 58720256);     // 4096x5460 bf16
    short* gb   = (short*)(ws + 103448576);    // 4096x2752 bf16 (K-padded)
    short* vtb  = (short*)(ws + 125992960);    // 32x64x2048 bf16
    float* ct   = (float*)(ws + 134381568);    // 2048x32 f32
    float* st   = (float*)(ws + 134643712);    // 2048x32 f32
    short* qkvT = (short*)(ws + 134905856);    // 4 x [3072][1024] bf16
    short* woT  = (short*)(ws + 160071680);    // 4 x [1024][1024]
    short* fw1T = (short*)(ws + 168460288);    // 4 x [5504][1024]
    short* fw2T = (short*)(ws + 213549056);    // 4 x [1024][2752]
    short* logT = (short*)(ws + 236093440);    // [32000][1024]  (ends ~301.6MB)

    rope_table_k<<<256, 256, 0, stream>>>(ct, st);
    embed_k<<<4096, 256, 0, stream>>>(tokens, temb, x);

    // one-time (per launch) weight convert+transpose to bf16 [N][K]
    wconv_k<<<dim3(96, 32, 4), 256, 0, stream>>>(
        wqkv, qkvT, 1024, 3072, 1024, (size_t)1024 * 3072, (size_t)3072 * 1024);
    wconv_k<<<dim3(32, 32, 4), 256, 0, stream>>>(
        wo, woT, 1024, 1024, 1024, (size_t)1024 * 1024, (size_t)1024 * 1024);
    wconv_k<<<dim3(172, 32, 4), 256, 0, stream>>>(
        fw1, fw1T, 1024, 5460, 1024, (size_t)1024 * 5460, (size_t)5504 * 1024);
    wconv_k<<<dim3(32, 86, 4), 256, 0, stream>>>(
        fw2, fw2T, 2730, 1024, 2752, (size_t)2730 * 1024, (size_t)1024 * 2752);
    wconv_k<<<dim3(1000, 32, 1), 256, 0, stream>>>(
        lw, logT, 1024, 32000, 1024, 0, 0);

    for (int l = 0; l < 4; ++l) {
        rmsnorm_k<<<4096, 256, 0, stream>>>(x, anw + l * 1024, hb);
        gemm2<false, false, true><<<32 * 24, 256, 0, stream>>>(
            hb, qkvT + (size_t)l * 3072 * 1024, nullptr, nullptr, qkv, 3072, 1024, 1024, 32);
        rope_apply_k<<<16384, 256, 0, stream>>>(qkv, ct, st);
        vt_k<<<256, 256, 0, stream>>>(qkv, vtb);
        attn_fwd<<<dim3(16, 32), 256, 0, stream>>>(qkv, vtb, ao);
        gemm2<false, true, false><<<32 * 8, 256, 0, stream>>>(
            ao, woT + (size_t)l * 1024 * 1024, nullptr, x, x, 1024, 1024, 1024, 32);
        rmsnorm_k<<<4096, 256, 0, stream>>>(x, fnw + l * 1024, hb);
        gemm2<true, false, true><<<32 * 43, 256, 0, stream>>>(
            hb, fw1T + (size_t)l * 5504 * 1024, fb1 + l * 5460, nullptr, ub, 5460, 1024, 1024, 32);
        geglu_k<<<dim3(4096, 11), 256, 0, stream>>>(ub, gb);
        gemm2<true, true, false><<<32 * 8, 256, 0, stream>>>(
            gb, fw2T + (size_t)l * 1024 * 2752, fb2 + l * 1024, x, x, 1024, 2752, 2752, 86);
    }
    rmsnorm_k<<<4096, 256, 0, stream>>>(x, finw, hb);
    gemm2<true, false, false><<<32 * 250, 256, 0, stream>>>(
        hb, logT, lb, nullptr, d_out, 32000, 1024, 1024, 32);
}

// Round 4
// 2058.943 us; speedup vs baseline: 1.5660x; 1.0225x over previous
//
#include <hip/hip_runtime.h>
#include <math.h>
#include <stdint.h>

// Llama forward on MI355X. Round 4: fix gemm3 final-iteration vmcnt drain race
// (last K-tile was read from LDS before global_load_lds landed).

using short8v = __attribute__((ext_vector_type(8))) short;
using f32x4   = __attribute__((ext_vector_type(4))) float;

__device__ __forceinline__ float b2f(short s) {
    union { unsigned u; float f; } v; v.u = ((unsigned)(unsigned short)s) << 16; return v.f;
}
__device__ __forceinline__ short f2b(float f) {
    union { float f; unsigned u; } v; v.f = f;
    unsigned r = v.u + 0x7FFFu + ((v.u >> 16) & 1u);
    return (short)(r >> 16);
}

__device__ __forceinline__ void mfma_n(f32x4& d, short8v a, short8v b) {
    asm("v_mfma_f32_16x16x32_bf16 %0, %1, %2, %0" : "+v"(d) : "v"(a), "v"(b));
}
__device__ __forceinline__ void mfma_f(f32x4& d, short8v a, short8v b) {
    asm("s_nop 1\n\tv_mfma_f32_16x16x32_bf16 %0, %1, %2, %0" : "+v"(d) : "v"(a), "v"(b));
}
#define MFMA_FENCE() do { __builtin_amdgcn_sched_barrier(0); \
    asm volatile("s_nop 7\n\ts_nop 7"); \
    __builtin_amdgcn_sched_barrier(0); } while (0)

__device__ __forceinline__ void gload16(const void* g, void* l) {
    __builtin_amdgcn_global_load_lds(
        (const __attribute__((address_space(1))) unsigned int*)(uintptr_t)g,
        (__attribute__((address_space(3))) unsigned int*)(uintptr_t)l,
        16, 0, 0);
}

#define BARX() do { asm volatile("" ::: "memory"); \
    __builtin_amdgcn_s_barrier(); asm volatile("" ::: "memory"); } while (0)
#define VMN(n) asm volatile("s_waitcnt vmcnt(" #n ")" ::: "memory")
#define LGKM0() do { asm volatile("s_waitcnt lgkmcnt(0)" ::: "memory"); \
    __builtin_amdgcn_sched_barrier(0); } while (0)

// ---------------- rope tables ----------------
__global__ void rope_table_k(float* __restrict__ ct, float* __restrict__ st) {
    int i = blockIdx.x * 256 + threadIdx.x;
    int n = i >> 5, j = i & 31;
    float freq = expf(-(float)j * (9.210340371976184f / 32.f));
    float a = (float)n * freq;
    ct[i] = cosf(a);
    st[i] = sinf(a);
}

// ---------------- embedding gather ----------------
__global__ void embed_k(const int* __restrict__ tok, const float* __restrict__ emb,
                        float* __restrict__ x) {
    int row = blockIdx.x;
    int tk = tok[row];
    const float4* src = (const float4*)(emb + (size_t)tk * 1024);
    float4* dst = (float4*)(x + (size_t)row * 1024);
    dst[threadIdx.x] = src[threadIdx.x];
}

// ---------------- weight convert+transpose: f32 [K][N] -> bf16 [Npad][Kpad] ----------------
__global__ void wconv_k(const float* __restrict__ W, short* __restrict__ T,
                        int K, int N, int Kpad,
                        size_t w_lstride, size_t t_lstride) {
    W += blockIdx.z * w_lstride;
    T += blockIdx.z * t_lstride;
    int n0 = blockIdx.x * 32, k0 = blockIdx.y * 32;
    __shared__ float tile[32][33];
    int t = threadIdx.x;
    int kk = t >> 3, ns = (t & 7) * 4;
    float4 v = make_float4(0.f, 0.f, 0.f, 0.f);
    int gk = k0 + kk;
    if (gk < K) {
        if (n0 + ns + 3 < N) {
            v = *(const float4*)(W + (size_t)gk * N + n0 + ns);
        } else {
            float tmp[4] = {0.f, 0.f, 0.f, 0.f};
            #pragma unroll
            for (int j = 0; j < 4; ++j)
                if (n0 + ns + j < N) tmp[j] = W[(size_t)gk * N + n0 + ns + j];
            v = make_float4(tmp[0], tmp[1], tmp[2], tmp[3]);
        }
    }
    tile[kk][ns + 0] = v.x; tile[kk][ns + 1] = v.y;
    tile[kk][ns + 2] = v.z; tile[kk][ns + 3] = v.w;
    __syncthreads();
    int nn = t >> 3, ks = (t & 7) * 4;
    short o[4];
    #pragma unroll
    for (int j = 0; j < 4; ++j) o[j] = f2b(tile[ks + j][nn]);
    *(int2*)(T + (size_t)(n0 + nn) * Kpad + k0 + ks) = *(int2*)o;
}

// ---------------- rmsnorm: f32 in -> bf16 out ----------------
__global__ void rmsnorm_k(const float* __restrict__ x, const float* __restrict__ wt,
                          short* __restrict__ out) {
    int row = blockIdx.x;
    int t = threadIdx.x;
    const float* xr = x + (size_t)row * 1024;
    float4 v = ((const float4*)xr)[t];
    float ss = v.x * v.x + v.y * v.y + v.z * v.z + v.w * v.w;
    #pragma unroll
    for (int off = 32; off > 0; off >>= 1) ss += __shfl_down(ss, off, 64);
    __shared__ float red[4];
    if ((t & 63) == 0) red[t >> 6] = ss;
    __syncthreads();
    float tot = red[0] + red[1] + red[2] + red[3];
    float inv = rsqrtf(tot * (1.f / 1024.f) + 1.1920929e-7f);
    float4 wv = ((const float4*)wt)[t];
    int2 pk;
    pk.x = (int)(unsigned short)f2b(v.x * inv * wv.x) |
           ((int)(unsigned short)f2b(v.y * inv * wv.y) << 16);
    pk.y = (int)(unsigned short)f2b(v.z * inv * wv.z) |
           ((int)(unsigned short)f2b(v.w * inv * wv.w) << 16);
    *(int2*)(out + (size_t)row * 1024 + t * 4) = pk;
}

// ---------------- rope apply ----------------
__global__ void rope_apply_k(short* __restrict__ qkv, const float* __restrict__ ct,
                             const float* __restrict__ st) {
    int gidx = blockIdx.x * 256 + threadIdx.x;
    int j  = gidx & 31;
    int r  = (gidx >> 5) & 4095;
    int hk = gidx >> 17;
    int qk = hk >> 4, h = hk & 15;
    int n = r & 2047;
    size_t base = (size_t)r * 3072 + (size_t)qk * 1024 + h * 64 + j;
    float a  = b2f(qkv[base]);
    float bv = b2f(qkv[base + 32]);
    float cc = ct[n * 32 + j], sv = st[n * 32 + j];
    float na = a * cc - bv * sv;
    float nb = bv * cc + a * sv;
    if (qk == 0) { na *= 0.125f; nb *= 0.125f; }
    qkv[base]      = f2b(na);
    qkv[base + 32] = f2b(nb);
}

// ---------------- V transpose ----------------
__global__ void vt_k(const short* __restrict__ qkv, short* __restrict__ vt) {
    int id = blockIdx.x * 256 + threadIdx.x;
    int dt = id & 7, nt = (id >> 3) & 255, bh = id >> 11;
    int b = bh >> 4, h = bh & 15;
    short s[8][8];
    #pragma unroll
    for (int r = 0; r < 8; ++r)
        *(int4*)s[r] = *(const int4*)(qkv + (size_t)(b * 2048 + nt * 8 + r) * 3072
                                      + 2048 + h * 64 + dt * 8);
    #pragma unroll
    for (int cc = 0; cc < 8; ++cc) {
        short o4[8];
        #pragma unroll
        for (int r = 0; r < 8; ++r) o4[r] = s[r][cc];
        *(int4*)(vt + (size_t)(bh * 64 + dt * 8 + cc) * 2048 + nt * 8) = *(int4*)o4;
    }
}

// ---------------- GEGLU ----------------
__global__ void geglu_k(const short* __restrict__ u, short* __restrict__ gbuf) {
    int r = blockIdx.x;
    int c = blockIdx.y * 256 + threadIdx.x;
    if (c >= 2752) return;
    float v = 0.f;
    if (c < 2730) {
        float u1 = b2f(u[(size_t)r * 5460 + c]);
        float gt = b2f(u[(size_t)r * 5460 + 2730 + c]);
        v = 0.5f * gt * (1.f + erff(gt * 0.7071067811865475f)) * u1;
    }
    gbuf[(size_t)r * 2752 + c] = f2b(v);
}

// ---------------- gemm2: 128x128 drain-style (kept for wo, ff2) ----------------
template <bool BIAS, bool RES, bool OUTBF16>
__global__ __launch_bounds__(256, 2) void gemm2(
    const short* __restrict__ A, const short* __restrict__ Bt,
    const float* __restrict__ bias, const float* __restrict__ res,
    void* __restrict__ outp, int N, int lda, int ldb, int ksteps) {
    __shared__ __align__(16) short As[128 * 32];
    __shared__ __align__(16) short Bs[128 * 32];
    const int t = threadIdx.x;
    const int lane = t & 63;
    const int w = t >> 6, wm = w >> 1, wn = w & 1;
    const int c = lane & 15, g = lane >> 4;

    const int nwg = (int)gridDim.x;
    const int cpx = nwg >> 3;
    const int wg = ((int)blockIdx.x & 7) * cpx + ((int)blockIdx.x >> 3);
    const int m0 = (wg & 31) << 7;
    const int n0 = (wg >> 5) << 7;

    const int srow = w * 32 + (lane >> 2);
    const int sseg = (lane & 3) * 8;
    const short* ga0 = A  + (size_t)(m0 + srow) * lda + sseg;
    const short* ga1 = A  + (size_t)(m0 + srow + 16) * lda + sseg;
    const short* gb0 = Bt + (size_t)(n0 + srow) * ldb + sseg;
    const short* gb1 = Bt + (size_t)(n0 + srow + 16) * ldb + sseg;
    short* la0 = &As[(w * 2 + 0) * 512];
    short* la1 = &As[(w * 2 + 1) * 512];
    short* lb0 = &Bs[(w * 2 + 0) * 512];
    short* lb1 = &Bs[(w * 2 + 1) * 512];

    f32x4 acc[4][4] = {};

    for (int kt = 0; kt < ksteps; ++kt) {
        const int k0 = kt << 5;
        __syncthreads();
        gload16(ga0 + k0, la0);
        gload16(ga1 + k0, la1);
        gload16(gb0 + k0, lb0);
        gload16(gb1 + k0, lb1);
        __syncthreads();
        short8v af[4], bf[4];
        #pragma unroll
        for (int mi = 0; mi < 4; ++mi)
            af[mi] = *(const short8v*)&As[(wm * 64 + mi * 16 + c) * 32 + g * 8];
        #pragma unroll
        for (int ni = 0; ni < 4; ++ni)
            bf[ni] = *(const short8v*)&Bs[(wn * 64 + ni * 16 + c) * 32 + g * 8];
        #pragma unroll
        for (int mi = 0; mi < 4; ++mi)
            #pragma unroll
            for (int ni = 0; ni < 4; ++ni)
                mfma_n(acc[mi][ni], af[mi], bf[ni]);
    }
    MFMA_FENCE();
    #pragma unroll
    for (int mi = 0; mi < 4; ++mi) {
        #pragma unroll
        for (int ni = 0; ni < 4; ++ni) {
            int col = n0 + wn * 64 + ni * 16 + c;
            if (col < N) {
                float bv = BIAS ? bias[col] : 0.f;
                #pragma unroll
                for (int i = 0; i < 4; ++i) {
                    int row = m0 + wm * 64 + mi * 16 + g * 4 + i;
                    size_t off = (size_t)row * N + col;
                    float v = acc[mi][ni][i] + bv;
                    if (RES) v += res[off];
                    if (OUTBF16) ((short*)outp)[off] = f2b(v);
                    else         ((float*)outp)[off] = v;
                }
            }
        }
    }
}

// ---------------- gemm3: 8-phase counted-vmcnt 128x256, BK=64, 8 waves ----------------
// vmcnt ledger (loads; STB=2, STA=1): steady-state queue depth 8..10, VM(6) at
// ph2/4/6/8 retires exactly the batch the next phase reads. Final iteration
// (no new stages) must drain explicitly: VM(2) at ph2 (retire last B p=1),
// VM(0) at ph4 (retire last A p=1) — round-3 bug was VM(6) no-op there.
template <bool BIAS, bool RES, bool OUTBF16>
__global__ __launch_bounds__(512, 1) void gemm3(
    const short* __restrict__ A, const short* __restrict__ Bt,
    const float* __restrict__ bias, const float* __restrict__ res,
    void* __restrict__ outp, int N, int lda, int ldb, int nrowsB, int KT) {
    __shared__ __align__(16) short L[49152];
    const int t = threadIdx.x;
    const int lane = t & 63;
    const int w = t >> 6;
    const int wm = w >> 2, wn = w & 3;
    const int c = lane & 15, g = lane >> 4;

    const int nwg = (int)gridDim.x, cpx = nwg >> 3;
    const int wg = ((int)blockIdx.x & 7) * cpx + ((int)blockIdx.x >> 3);
    const int m0 = (wg & 31) << 7;          // M/128 = 32, m-fastest
    const int n0 = (wg >> 5) << 8;

    const int rS = t >> 3, sS = t & 7;
    const int sSw = (sS ^ (rS & 7)) << 3;   // swizzled col (shorts)
    size_t aoffh[2], broff[2][2];
    #pragma unroll
    for (int h = 0; h < 2; ++h)
        aoffh[h] = (size_t)(m0 + h * 64 + rS) * lda + sSw;
    #pragma unroll
    for (int h = 0; h < 2; ++h)
        #pragma unroll
        for (int i = 0; i < 2; ++i) {
            int brow = n0 + h * 128 + rS + i * 64;
            if (brow > nrowsB - 1) brow = nrowsB - 1;
            broff[h][i] = (size_t)brow * ldb + sSw;
        }
    short* ldsA[2][2];  // [p][h]
    short* ldsB[2][2];
    #pragma unroll
    for (int p = 0; p < 2; ++p)
        #pragma unroll
        for (int h = 0; h < 2; ++h) {
            ldsA[p][h] = &L[(p * 2 + h) * 4096 + w * 512];
            ldsB[p][h] = &L[16384 + (p * 2 + h) * 8192 + w * 512];
        }

    const int cb0 = ((g * 8) ^ ((c & 7) * 8));
    const int vbA0 = wm * 4096 + c * 64 + cb0;
    const int vbA1 = vbA0 ^ 32;
    const int vbB0 = 16384 + (wn >> 1) * 8192 + (wn & 1) * 4096 + c * 64 + cb0;
    const int vbB1 = vbB0 ^ 32;

    #define STA3(p, h, kt) gload16(A + aoffh[h] + (kt) * 64, ldsA[p][h])
    #define STB3(p, h, kt) do { \
        gload16(Bt + broff[h][0] + (kt) * 64, ldsB[p][h]); \
        gload16(Bt + broff[h][1] + (kt) * 64, ldsB[p][h] + 4096); } while (0)
    #define LDA3(p, mi, ks) (*(const short8v*)&L[(p) * 8192 + (mi) * 1024 + ((ks) ? vbA1 : vbA0)])
    #define LDB3(p, ni, ks) (*(const short8v*)&L[(p) * 16384 + (ni) * 1024 + ((ks) ? vbB1 : vbB0)])
    #define MFMA8(MLO, NLO, BV) do { \
        _Pragma("unroll") for (int ks_ = 0; ks_ < 2; ++ks_) \
        _Pragma("unroll") for (int mi_ = 0; mi_ < 2; ++mi_) \
        _Pragma("unroll") for (int ni_ = 0; ni_ < 2; ++ni_) \
            mfma_n(acc[(MLO) + mi_][(NLO) + ni_], av[(MLO) + mi_][ks_], BV[(NLO) + ni_][ks_]); \
        } while (0)

    f32x4 acc[4][4] = {};
    short8v av[4][2], bc[4][2], bn[4][2];

    // prologue: stage both pipeline slots (12 loads outstanding)
    STB3(0, 1, 0); STB3(0, 0, 0); STA3(0, 0, 0); STA3(0, 1, 0);
    STB3(1, 1, 1); STB3(1, 0, 1); STA3(1, 0, 1); STA3(1, 1, 1);
    VMN(6);
    BARX();
    #pragma unroll
    for (int ni = 0; ni < 4; ++ni)
        #pragma unroll
        for (int ks = 0; ks < 2; ++ks)
            bc[ni][ks] = LDB3(0, ni, ks);
    LGKM0();
    BARX();
    asm volatile("s_nop 7\n\ts_nop 7");   // acc-init VALU -> first MFMA srcC

    for (int KB = 0; KB < KT; KB += 2) {
        const bool st1 = (KB + 2 < KT);
        const bool st2 = (KB + 3 < KT);
        // ph1
        #pragma unroll
        for (int mi = 0; mi < 2; ++mi)
            #pragma unroll
            for (int ks = 0; ks < 2; ++ks) av[mi][ks] = LDA3(0, mi, ks);
        if (st1) STB3(0, 1, KB + 2);
        BARX();
        __builtin_amdgcn_s_setprio(1); MFMA8(0, 0, bc); __builtin_amdgcn_s_setprio(0);
        BARX();
        // ph2
        #pragma unroll
        for (int mi = 2; mi < 4; ++mi)
            #pragma unroll
            for (int ks = 0; ks < 2; ++ks) av[mi][ks] = LDA3(0, mi, ks);
        if (st1) { STB3(0, 0, KB + 2); VMN(6); } else { VMN(2); }
        BARX();
        __builtin_amdgcn_s_setprio(1); MFMA8(2, 0, bc); __builtin_amdgcn_s_setprio(0);
        BARX();
        // ph3
        #pragma unroll
        for (int ni = 0; ni < 2; ++ni)
            #pragma unroll
            for (int ks = 0; ks < 2; ++ks) bn[ni][ks] = LDB3(1, ni, ks);
        if (st1) STA3(0, 0, KB + 2);
        BARX();
        __builtin_amdgcn_s_setprio(1); MFMA8(0, 2, bc); __builtin_amdgcn_s_setprio(0);
        BARX();
        // ph4
        #pragma unroll
        for (int ni = 2; ni < 4; ++ni)
            #pragma unroll
            for (int ks = 0; ks < 2; ++ks) bn[ni][ks] = LDB3(1, ni, ks);
        if (st1) { STA3(0, 1, KB + 2); VMN(6); } else { VMN(0); }
        BARX();
        __builtin_amdgcn_s_setprio(1); MFMA8(2, 2, bc); __builtin_amdgcn_s_setprio(0);
        BARX();
        // ph5
        #pragma unroll
        for (int mi = 0; mi < 2; ++mi)
            #pragma unroll
            for (int ks = 0; ks < 2; ++ks) av[mi][ks] = LDA3(1, mi, ks);
        if (st2) STB3(1, 1, KB + 3);
        BARX();
        __builtin_amdgcn_s_setprio(1); MFMA8(0, 0, bn); __builtin_amdgcn_s_setprio(0);
        BARX();
        // ph6
        #pragma unroll
        for (int mi = 2; mi < 4; ++mi)
            #pragma unroll
            for (int ks = 0; ks < 2; ++ks) av[mi][ks] = LDA3(1, mi, ks);
        if (st2) STB3(1, 0, KB + 3);
        if (st1) VMN(6);
        BARX();
        __builtin_amdgcn_s_setprio(1); MFMA8(2, 0, bn); __builtin_amdgcn_s_setprio(0);
        BARX();
        // ph7
        if (st1) {
            #pragma unroll
            for (int ni = 0; ni < 2; ++ni)
                #pragma unroll
                for (int ks = 0; ks < 2; ++ks) bc[ni][ks] = LDB3(0, ni, ks);
        }
        if (st2) STA3(1, 0, KB + 3);
        BARX();
        __builtin_amdgcn_s_setprio(1); MFMA8(0, 2, bn); __builtin_amdgcn_s_setprio(0);
        BARX();
        // ph8
        if (st1) {
            #pragma unroll
            for (int ni = 2; ni < 4; ++ni)
                #pragma unroll
                for (int ks = 0; ks < 2; ++ks) bc[ni][ks] = LDB3(0, ni, ks);
        }
        if (st2) STA3(1, 1, KB + 3);
        if (st1) VMN(6);
        BARX();
        __builtin_amdgcn_s_setprio(1); MFMA8(2, 2, bn); __builtin_amdgcn_s_setprio(0);
        BARX();
    }

    MFMA_FENCE();
    #pragma unroll
    for (int mi = 0; mi < 4; ++mi) {
        #pragma unroll
        for (int ni = 0; ni < 4; ++ni) {
            int col = n0 + wn * 64 + ni * 16 + c;
            if (col < N) {
                float bv = BIAS ? bias[col] : 0.f;
                #pragma unroll
                for (int i = 0; i < 4; ++i) {
                    int row = m0 + wm * 64 + mi * 16 + g * 4 + i;
                    size_t off = (size_t)row * N + col;
                    float v = acc[mi][ni][i] + bv;
                    if (RES) v += res[off];
                    if (OUTBF16) ((short*)outp)[off] = f2b(v);
                    else         ((float*)outp)[off] = v;
                }
            }
        }
    }
    #undef STA3
    #undef STB3
    #undef LDA3
    #undef LDB3
    #undef MFMA8
}

// ---------------- flash attention ----------------
__global__ __launch_bounds__(256, 2) void attn_fwd(
    const short* __restrict__ qkv, const short* __restrict__ vt,
    short* __restrict__ o) {
    const int qt = blockIdx.x, bh = blockIdx.y;
    const int b = bh >> 4, h = bh & 15;
    const int t = threadIdx.x, lane = t & 63, w = t >> 6;
    const int c = lane & 15, g = lane >> 4;
    __shared__ __align__(16) short Ks[128 * 72];
    __shared__ __align__(16) short Vs[64 * 136];
    __shared__ __align__(16) short Ps[128 * 136];

    #pragma unroll
    for (int i = 0; i < 4; ++i) {
        int idx = t + i * 256, r = idx >> 3, seg = idx & 7;
        *(int4*)&Ps[r * 136 + seg * 8] =
            *(const int4*)(qkv + (size_t)(b * 2048 + qt * 128 + r) * 3072 + h * 64 + seg * 8);
    }
    __syncthreads();
    short8v qf[2][2];
    #pragma unroll
    for (int mi = 0; mi < 2; ++mi)
        #pragma unroll
        for (int kk = 0; kk < 2; ++kk)
            qf[mi][kk] = *(const short8v*)&Ps[(w * 32 + mi * 16 + c) * 136 + kk * 32 + g * 8];

    f32x4 oacc[2][4] = {};
    float mrow[2][4], lrow[2][4];
    #pragma unroll
    for (int mi = 0; mi < 2; ++mi)
        #pragma unroll
        for (int i = 0; i < 4; ++i) { mrow[mi][i] = -3.0e38f; lrow[mi][i] = 0.f; }

    for (int jt = 0; jt <= qt; ++jt) {
        __syncthreads();
        #pragma unroll
        for (int i = 0; i < 4; ++i) {
            int idx = t + i * 256, r = idx >> 3, seg = idx & 7;
            *(int4*)&Ks[r * 72 + seg * 8] =
                *(const int4*)(qkv + (size_t)(b * 2048 + jt * 128 + r) * 3072
                               + 1024 + h * 64 + seg * 8);
        }
        #pragma unroll
        for (int i = 0; i < 4; ++i) {
            int idx = t + i * 256, d = idx >> 4, seg = idx & 15;
            *(int4*)&Vs[d * 136 + seg * 8] =
                *(const int4*)(vt + (size_t)(bh * 64 + d) * 2048 + jt * 128 + seg * 8);
        }
        __syncthreads();
        f32x4 sacc[2][8] = {};
        #pragma unroll
        for (int kk = 0; kk < 2; ++kk) {
            short8v kf[8];
            #pragma unroll
            for (int ni = 0; ni < 8; ++ni)
                kf[ni] = *(const short8v*)&Ks[(ni * 16 + c) * 72 + kk * 32 + g * 8];
            #pragma unroll
            for (int mi = 0; mi < 2; ++mi)
                #pragma unroll
                for (int ni = 0; ni < 8; ++ni) {
                    if (kk == 0) mfma_f(sacc[mi][ni], qf[mi][kk], kf[ni]);
                    else         mfma_n(sacc[mi][ni], qf[mi][kk], kf[ni]);
                }
        }
        MFMA_FENCE();
        if (jt == qt) {
            #pragma unroll
            for (int mi = 0; mi < 2; ++mi)
                #pragma unroll
                for (int ni = 0; ni < 8; ++ni)
                    #pragma unroll
                    for (int i = 0; i < 4; ++i) {
                        int qrow = w * 32 + mi * 16 + g * 4 + i;
                        int kcol = ni * 16 + c;
                        if (kcol > qrow) sacc[mi][ni][i] = -3.0e38f;
                    }
        }
        #pragma unroll
        for (int mi = 0; mi < 2; ++mi) {
            #pragma unroll
            for (int i = 0; i < 4; ++i) {
                float mx = sacc[mi][0][i];
                #pragma unroll
                for (int ni = 1; ni < 8; ++ni) mx = fmaxf(mx, sacc[mi][ni][i]);
                #pragma unroll
                for (int off = 1; off < 16; off <<= 1) mx = fmaxf(mx, __shfl_xor(mx, off, 64));
                float mnew = fmaxf(mrow[mi][i], mx);
                float alpha = __expf(mrow[mi][i] - mnew);
                mrow[mi][i] = mnew;
                float ls = 0.f;
                #pragma unroll
                for (int ni = 0; ni < 8; ++ni) {
                    float p = __expf(sacc[mi][ni][i] - mnew);
                    sacc[mi][ni][i] = p;
                    ls += p;
                }
                #pragma unroll
                for (int off = 1; off < 16; off <<= 1) ls += __shfl_xor(ls, off, 64);
                lrow[mi][i] = lrow[mi][i] * alpha + ls;
                #pragma unroll
                for (int df = 0; df < 4; ++df) oacc[mi][df][i] *= alpha;
            }
        }
        #pragma unroll
        for (int mi = 0; mi < 2; ++mi)
            #pragma unroll
            for (int ni = 0; ni < 8; ++ni)
                #pragma unroll
                for (int i = 0; i < 4; ++i)
                    Ps[(w * 32 + mi * 16 + g * 4 + i) * 136 + ni * 16 + c] =
                        f2b(sacc[mi][ni][i]);
        #pragma unroll
        for (int kk = 0; kk < 4; ++kk) {
            short8v pf[2], vf[4];
            #pragma unroll
            for (int mi = 0; mi < 2; ++mi)
                pf[mi] = *(const short8v*)&Ps[(w * 32 + mi * 16 + c) * 136 + kk * 32 + g * 8];
            #pragma unroll
            for (int df = 0; df < 4; ++df)
                vf[df] = *(const short8v*)&Vs[(df * 16 + c) * 136 + kk * 32 + g * 8];
            #pragma unroll
            for (int mi = 0; mi < 2; ++mi)
                #pragma unroll
                for (int df = 0; df < 4; ++df) {
                    if (kk == 0) mfma_f(oacc[mi][df], pf[mi], vf[df]);
                    else         mfma_n(oacc[mi][df], pf[mi], vf[df]);
                }
        }
    }
    MFMA_FENCE();
    #pragma unroll
    for (int mi = 0; mi < 2; ++mi)
        #pragma unroll
        for (int df = 0; df < 4; ++df)
            #pragma unroll
            for (int i = 0; i < 4; ++i) {
                int qrow = qt * 128 + w * 32 + mi * 16 + g * 4 + i;
                float v = oacc[mi][df][i] / lrow[mi][i];
                o[(size_t)(b * 2048 + qrow) * 1024 + h * 64 + df * 16 + c] = f2b(v);
            }
}

extern "C" void kernel_launch(void* const* d_in, const int* in_sizes, int n_in,
                              void* d_out, int out_size, void* d_ws, size_t ws_size,
                              hipStream_t stream) {
    (void)in_sizes; (void)n_in; (void)out_size; (void)ws_size;
    const int*   tokens = (const int*)d_in[0];
    const float* temb   = (const float*)d_in[1];
    const float* anw    = (const float*)d_in[2];
    const float* wqkv   = (const float*)d_in[3];
    const float* wo     = (const float*)d_in[4];
    const float* fnw    = (const float*)d_in[5];
    const float* fw1    = (const float*)d_in[6];
    const float* fb1    = (const float*)d_in[7];
    const float* fw2    = (const float*)d_in[8];
    const float* fb2    = (const float*)d_in[9];
    const float* finw   = (const float*)d_in[10];
    const float* lw     = (const float*)d_in[11];
    const float* lb     = (const float*)d_in[12];

    char* ws = (char*)d_ws;
    float* x    = (float*)(ws + 0);            // 4096x1024 f32
    short* hb   = (short*)(ws + 16777216);     // 4096x1024 bf16
    short* qkv  = (short*)(ws + 25165824);     // 4096x3072 bf16
    short* ao   = (short*)(ws + 50331648);     // 4096x1024 bf16
    short* ub   = (short*)(ws + 58720256);     // 4096x5460 bf16
    short* gb   = (short*)(ws + 103448576);    // 4096x2752 bf16 (K-padded)
    short* vtb  = (short*)(ws + 125992960);    // 32x64x2048 bf16
    float* ct   = (float*)(ws + 134381568);    // 2048x32 f32
    float* st   = (float*)(ws + 134643712);    // 2048x32 f32
    short* qkvT = (short*)(ws + 134905856);    // 4 x [3072][1024] bf16
    short* woT  = (short*)(ws + 160071680);    // 4 x [1024][1024]
    short* fw1T = (short*)(ws + 168460288);    // 4 x [5504][1024]
    short* fw2T = (short*)(ws + 213549056);    // 4 x [1024][2752]
    short* logT = (short*)(ws + 236093440);    // [32000][1024]

    rope_table_k<<<256, 256, 0, stream>>>(ct, st);
    embed_k<<<4096, 256, 0, stream>>>(tokens, temb, x);

    wconv_k<<<dim3(96, 32, 4), 256, 0, stream>>>(
        wqkv, qkvT, 1024, 3072, 1024, (size_t)1024 * 3072, (size_t)3072 * 1024);
    wconv_k<<<dim3(32, 32, 4), 256, 0, stream>>>(
        wo, woT, 1024, 1024, 1024, (size_t)1024 * 1024, (size_t)1024 * 1024);
    wconv_k<<<dim3(172, 32, 4), 256, 0, stream>>>(
        fw1, fw1T, 1024, 5460, 1024, (size_t)1024 * 5460, (size_t)5504 * 1024);
    wconv_k<<<dim3(32, 86, 4), 256, 0, stream>>>(
        fw2, fw2T, 2730, 1024, 2752, (size_t)2730 * 1024, (size_t)1024 * 2752);
    wconv_k<<<dim3(1000, 32, 1), 256, 0, stream>>>(
        lw, logT, 1024, 32000, 1024, 0, 0);

    for (int l = 0; l < 4; ++l) {
        rmsnorm_k<<<4096, 256, 0, stream>>>(x, anw + l * 1024, hb);
        gemm3<false, false, true><<<32 * 12, 512, 0, stream>>>(
            hb, qkvT + (size_t)l * 3072 * 1024, nullptr, nullptr, qkv,
            3072, 1024, 1024, 3072, 16);
        rope_apply_k<<<16384, 256, 0, stream>>>(qkv, ct, st);
        vt_k<<<256, 256, 0, stream>>>(qkv, vtb);
        attn_fwd<<<dim3(16, 32), 256, 0, stream>>>(qkv, vtb, ao);
        gemm2<false, true, false><<<32 * 8, 256, 0, stream>>>(
            ao, woT + (size_t)l * 1024 * 1024, nullptr, x, x, 1024, 1024, 1024, 32);
        rmsnorm_k<<<4096, 256, 0, stream>>>(x, fnw + l * 1024, hb);
        gemm3<true, false, true><<<32 * 22, 512, 0, stream>>>(
            hb, fw1T + (size_t)l * 5504 * 1024, fb1 + l * 5460, nullptr, ub,
            5460, 1024, 1024, 5504, 16);
        geglu_k<<<dim3(4096, 11), 256, 0, stream>>>(ub, gb);
        gemm2<true, true, false><<<32 * 8, 256, 0, stream>>>(
            gb, fw2T + (size_t)l * 1024 * 2752, fb2 + l * 1024, x, x, 1024, 2752, 2752, 86);
    }
    rmsnorm_k<<<4096, 256, 0, stream>>>(x, finw, hb);
    gemm3<true, false, false><<<32 * 125, 512, 0, stream>>>(
        hb, logT, lb, nullptr, d_out, 32000, 1024, 1024, 32000, 16);
}